// Round 4
// baseline (221.684 us; speedup 1.0000x reference)
//
#include <hip/hip_runtime.h>

typedef _Float16 f16;
typedef _Float16 f16x8 __attribute__((ext_vector_type(8)));
typedef __bf16 bf16x8 __attribute__((ext_vector_type(8)));
typedef float floatx4 __attribute__((ext_vector_type(4)));
typedef unsigned short u16;

#define B_N   8
#define T_SEQ 4096
#define DIM   64
#define QT    64     // q rows per block
#define NIT   32     // 4096 / (128 keys per iter: 32 per wave x 4 key-subgroup waves)
#define XSTR  72     // prep LDS row stride in u16
#define LOG2E 1.44269504f
#define FRAG  512    // fragment = 512 u16 (1 KB): lane holds its 8 u16 at lane*8

#if __has_builtin(__builtin_amdgcn_exp2f)
#define EXP2(x) __builtin_amdgcn_exp2f(x)
#else
#define EXP2(x) exp2f(x)
#endif

typedef __attribute__((address_space(1))) const void gvoid;
typedef __attribute__((address_space(3))) void svoid;

// ---- prep: fragment-major Kswz (slot-permuted), Qswz (f16, pre-scaled by log2e),
// ---- Vswz (bf16 V^T B-fragments, identity key order) ----
__launch_bounds__(256, 2)
__global__ void prep_kernel(const float* __restrict__ X, const float* __restrict__ W,
                            u16* __restrict__ Kswz, u16* __restrict__ Qswz,
                            u16* __restrict__ Vswz) {
  __shared__ __attribute__((aligned(16))) u16 Xs[DIM * XSTR];  // f16 X tile [t][d]
  __shared__ __attribute__((aligned(16))) u16 Wt[DIM * XSTR];  // f16 W^T [e][d]
  __shared__ __attribute__((aligned(16))) u16 Qs[DIM * XSTR];  // f16 Q tile [t][e]
  const int tid = threadIdx.x;
  const int lane = tid & 63, w = tid >> 6, qd = lane >> 4, ln = lane & 15;
  const int b = blockIdx.y;
  const int t0 = blockIdx.x * 64;
  const long xbase = ((long)b * T_SEQ + t0) * DIM;

  {
    const int r = tid >> 2, c0 = (tid & 3) * 16;
    float v[16];
#pragma unroll
    for (int i = 0; i < 4; i++)
      *(float4*)&v[i * 4] = *(const float4*)(X + xbase + (long)r * DIM + c0 + i * 4);
    u16 h[16];
#pragma unroll
    for (int j = 0; j < 16; j++) h[j] = __builtin_bit_cast(u16, (f16)v[j]);
    *(uint4*)&Xs[r * XSTR + c0] = *(uint4*)&h[0];
    *(uint4*)&Xs[r * XSTR + c0 + 8] = *(uint4*)&h[8];
    float wv[16];
#pragma unroll
    for (int i = 0; i < 4; i++)
      *(float4*)&wv[i * 4] = *(const float4*)(W + r * DIM + c0 + i * 4);
#pragma unroll
    for (int j = 0; j < 16; j++) Wt[(c0 + j) * XSTR + r] = __builtin_bit_cast(u16, (f16)wv[j]);
  }
  __syncthreads();

  // K fragments, SLOT-PERMUTED: S^T C-layout slot s = ct*16 + qd*4 + r holds
  // physical key k(s) = ((s>>2)&3)*8 + (s>>4)*4 + (s&3) so PV's A-fragment
  // position k = qd*8 + ct*4 + r lines up with V's identity key order.
  {
    const int tile = w >> 1, ct = w & 1;           // 4 waves -> 2 tiles x 2 ct
    const int krow = tile * 32 + (ln >> 2) * 8 + ct * 4 + (ln & 3);
    const long F = ((long)b * 128 + blockIdx.x * 2 + tile) * 2 + ct;
#pragma unroll
    for (int ks = 0; ks < 2; ks++) {
      f16x8 kv = *(const f16x8*)&Xs[krow * XSTR + ks * 32 + qd * 8];
      *(f16x8*)(Kswz + (F * 2 + ks) * FRAG + lane * 8) = kv;
    }
  }

  // Q = X@W via MFMA, scaled by log2e, to Qs (wave-local rows)
  {
    const int wq = w * 16;
    floatx4 acc[4];
#pragma unroll
    for (int ct = 0; ct < 4; ct++) acc[ct] = (floatx4)0.0f;
#pragma unroll
    for (int ks = 0; ks < 2; ks++) {
      f16x8 aX = *(const f16x8*)&Xs[(wq + ln) * XSTR + ks * 32 + qd * 8];
#pragma unroll
      for (int ct = 0; ct < 4; ct++) {
        f16x8 bW = *(const f16x8*)&Wt[(ct * 16 + ln) * XSTR + ks * 32 + qd * 8];
        acc[ct] = __builtin_amdgcn_mfma_f32_16x16x32_f16(aX, bW, acc[ct], 0, 0, 0);
      }
    }
#pragma unroll
    for (int ct = 0; ct < 4; ct++)
#pragma unroll
      for (int r = 0; r < 4; r++)
        Qs[(wq + qd * 4 + r) * XSTR + ct * 16 + ln] =
            __builtin_bit_cast(u16, (f16)(acc[ct][r] * LOG2E));
  }

  // V fragments (identity key order): wave w -> d-block Cb = b*4+w
  {
    const long Cb = (long)b * 4 + w;
    const int J0 = blockIdx.x * 2;
#pragma unroll
    for (int J = 0; J < 2; J++) {
      bf16x8 vv;
#pragma unroll
      for (int j = 0; j < 8; j++) {
        f16 hv = __builtin_bit_cast(f16, Xs[(J * 32 + qd * 8 + j) * XSTR + w * 16 + ln]);
        vv[j] = (__bf16)(float)hv;
      }
      *(bf16x8*)(Vswz + (Cb * (T_SEQ / 32) + J0 + J) * FRAG + lane * 8) = vv;
    }
  }

  // Q fragments from Qs (wave-local rows — no barrier needed)
  {
    const long R = (long)b * (T_SEQ / 16) + blockIdx.x * 4 + w;
#pragma unroll
    for (int ks = 0; ks < 2; ks++) {
      f16x8 qv = *(const f16x8*)&Qs[(w * 16 + ln) * XSTR + ks * 32 + qd * 8];
      *(f16x8*)(Qswz + (R * 2 + ks) * FRAG + lane * 8) = qv;
    }
  }
}

// ---- main: 8 waves = 2 q-groups x 4 key-subgroups. K/V staged to LDS via
// global_load_lds (double-buffered, 1 barrier/iter). P stays in registers.
// Per iter: 128 keys (32/wk-subgroup), shared by both q-groups via LDS. ----
__launch_bounds__(512, 4)
__global__ void attn_kernel(const u16* __restrict__ Kswz, const u16* __restrict__ Qswz,
                            const u16* __restrict__ Vswz, float* __restrict__ out) {
  // staging: per buf 32 KB = 16 K-frags (16 KB) + 16 V-frags (16 KB), 1 KB each
  __shared__ __attribute__((aligned(16))) char sbuf[2][32768];
  __shared__ float lpart[8][32];
  float* Opart = (float*)&sbuf[0][0];  // epilogue alias: 8*16*68*4 = 34816 B <= 65536

  const int tid = threadIdx.x;
  const int lane = tid & 63;
  const int w = tid >> 6;           // 0..7
  const int qd = lane >> 4;
  const int ln = lane & 15;
  const int wg = w >> 2;            // q-group
  const int wk = w & 3;             // key subgroup
  const int bid = blockIdx.x;
  const int b = bid & 7;            // batch == XCD for L2 affinity
  const int q0 = (bid >> 3) * QT;
  const long bbase = (long)b * T_SEQ * DIM;

  // Q B-fragments pinned: 32 rows x 64 d for this q-group
  f16x8 aQ[2][2];
#pragma unroll
  for (int rb = 0; rb < 2; rb++)
#pragma unroll
    for (int ks = 0; ks < 2; ks++)
      aQ[rb][ks] = *(const f16x8*)(Qswz +
          (((long)b * (T_SEQ / 16) + (q0 >> 4) + wg * 2 + rb) * 2 + ks) * FRAG + lane * 8);

  // staging source bases (per-lane byte pointers)
  // K tile tau = t*4 + wk' lives at b*524288 + tau*4096 (4 x 1KB frags, i = ct*2+ks)
  // V frag (db, tau) at b*524288 + db*131072 + tau*1024  [wave 4..7 stages, i = db]
  const char* gKw = (const char*)Kswz + (long)b * 524288 + (long)w * 4096 + lane * 16;
  const char* gVw = (const char*)Vswz + (long)b * 524288 + (long)(w - 4) * 1024 + lane * 16;

#define STAGE(bufv, t)                                                                  \
  do {                                                                                  \
    if (w < 4) {                                                                        \
      const char* g = gKw + (long)(t) * 16384;                                          \
      char* l = &sbuf[bufv][w * 4096];                                                  \
      _Pragma("unroll") for (int i = 0; i < 4; i++)                                     \
          __builtin_amdgcn_global_load_lds((gvoid*)(g + i * 1024), (svoid*)(l + i * 1024), \
                                           16, 0, 0);                                   \
    } else {                                                                            \
      const char* g = gVw + (long)(t) * 4096;                                           \
      char* l = &sbuf[bufv][16384 + (w - 4) * 4096];                                    \
      _Pragma("unroll") for (int i = 0; i < 4; i++)                                     \
          __builtin_amdgcn_global_load_lds((gvoid*)(g + i * 131072), (svoid*)(l + i * 1024), \
                                           16, 0, 0);                                   \
    }                                                                                   \
  } while (0)

  floatx4 O[2][4];                  // [q 16-block][d 16-block], 32q x 64d per wave
  float lacc[2] = {0.f, 0.f};
#pragma unroll
  for (int rb = 0; rb < 2; rb++)
#pragma unroll
    for (int db = 0; db < 4; db++) O[rb][db] = (floatx4)0.0f;

  STAGE(0, 0);
  __syncthreads();

  int buf = 0;
#pragma unroll 1
  for (int t = 0; t < NIT; t++) {
    // prefetch next tile into the other buffer (async, drains at syncthreads)
    if (t + 1 < NIT) STAGE(buf ^ 1, t + 1);

    // LDS -> registers (linear 1 KB fragments: conflict-free b128 reads)
    const char* Kb = &sbuf[buf][wk * 4096];
    const char* Vb = &sbuf[buf][16384 + wk * 4096];
    f16x8 bK[2][2];
#pragma unroll
    for (int ct = 0; ct < 2; ct++)
#pragma unroll
      for (int ks = 0; ks < 2; ks++)
        bK[ct][ks] = *(const f16x8*)(Kb + (ct * 2 + ks) * 1024 + lane * 16);
    bf16x8 bV[4];
#pragma unroll
    for (int db = 0; db < 4; db++)
      bV[db] = *(const bf16x8*)(Vb + db * 1024 + lane * 16);

    // QK^T: S^T[32k x 32q]
    floatx4 St[2][2];
#pragma unroll
    for (int ct = 0; ct < 2; ct++)
#pragma unroll
      for (int rb = 0; rb < 2; rb++) St[ct][rb] = (floatx4)0.0f;
    __builtin_amdgcn_s_setprio(1);
#pragma unroll
    for (int ks = 0; ks < 2; ks++)
#pragma unroll
      for (int ct = 0; ct < 2; ct++)
#pragma unroll
        for (int rb = 0; rb < 2; rb++)
          St[ct][rb] = __builtin_amdgcn_mfma_f32_16x16x32_f16(bK[ct][ks], aQ[rb][ks], St[ct][rb], 0, 0, 0);
    __builtin_amdgcn_s_setprio(0);

    // P = 2^S' in registers: slot (ct,qd,r) -> A-frag element j = ct*4 + r
    bf16x8 pk[2];
#pragma unroll
    for (int rb = 0; rb < 2; rb++) {
      float ps = 0.f;
#pragma unroll
      for (int ct = 0; ct < 2; ct++)
#pragma unroll
        for (int r = 0; r < 4; r++) {
          float p = EXP2(St[ct][rb][r]);
          ps += p;
          pk[rb][ct * 4 + r] = (__bf16)p;
        }
      lacc[rb] += ps;
    }

    // PV: O[32q x 64d] += P[32q x 32k] V[32k x 64d]
    __builtin_amdgcn_s_setprio(1);
#pragma unroll
    for (int rb = 0; rb < 2; rb++)
#pragma unroll
      for (int db = 0; db < 4; db++)
        O[rb][db] = __builtin_amdgcn_mfma_f32_16x16x32_bf16(pk[rb], bV[db], O[rb][db], 0, 0, 0);
    __builtin_amdgcn_s_setprio(0);

    __syncthreads();  // drains vmcnt (stages landed) + lgkm; publishes buf^1
    buf ^= 1;
  }

  // l partials: reduce across qd lanes; lpart[w][q-local 0..31]
#pragma unroll
  for (int rb = 0; rb < 2; rb++) {
    float v = lacc[rb];
    v += __shfl_xor(v, 16, 64);
    v += __shfl_xor(v, 32, 64);
    if (qd == 0) lpart[w][rb * 16 + ln] = v;
  }

  // epilogue: 2 rounds (rb); sum 4 key-subgroup partials per q-group
#pragma unroll 1
  for (int rb = 0; rb < 2; rb++) {
    __syncthreads();  // rb=0: lpart published + last LDS reads done; rb=1: prior reads done
#pragma unroll
    for (int db = 0; db < 4; db++)
#pragma unroll
      for (int r = 0; r < 4; r++)
        Opart[(w * 16 + qd * 4 + r) * 68 + db * 16 + ln] = O[rb][db][r];
    __syncthreads();
    const int wg2 = tid >> 8;         // 0..1
    const int q2 = (tid >> 4) & 15;   // 0..15
    const int d0 = (tid & 15) * 4;    // 0..60
    float4 s = *(const float4*)&Opart[((wg2 * 4 + 0) * 16 + q2) * 68 + d0];
    const float4 s1 = *(const float4*)&Opart[((wg2 * 4 + 1) * 16 + q2) * 68 + d0];
    const float4 s2 = *(const float4*)&Opart[((wg2 * 4 + 2) * 16 + q2) * 68 + d0];
    const float4 s3 = *(const float4*)&Opart[((wg2 * 4 + 3) * 16 + q2) * 68 + d0];
    float l = lpart[wg2 * 4 + 0][rb * 16 + q2] + lpart[wg2 * 4 + 1][rb * 16 + q2] +
              lpart[wg2 * 4 + 2][rb * 16 + q2] + lpart[wg2 * 4 + 3][rb * 16 + q2];
    const float inv = 1.0f / l;
    float4 o;
    o.x = (s.x + s1.x + s2.x + s3.x) * inv;
    o.y = (s.y + s1.y + s2.y + s3.y) * inv;
    o.z = (s.z + s1.z + s2.z + s3.z) * inv;
    o.w = (s.w + s1.w + s2.w + s3.w) * inv;
    *(float4*)(out + bbase + (long)(q0 + wg2 * 32 + rb * 16 + q2) * DIM + d0) = o;
  }
#undef STAGE
}

extern "C" void kernel_launch(void* const* d_in, const int* in_sizes, int n_in,
                              void* d_out, int out_size, void* d_ws, size_t ws_size,
                              hipStream_t stream) {
  const float* X = (const float*)d_in[0];
  const float* W = (const float*)d_in[1];
  float* out = (float*)d_out;
  const size_t SZ = (size_t)B_N * T_SEQ * DIM * 2;  // 4 MB per u16 array
  u16* Kswz = (u16*)d_ws;
  u16* Qswz = (u16*)((char*)d_ws + SZ);
  u16* Vswz = (u16*)((char*)d_ws + 2 * SZ);
  prep_kernel<<<dim3(T_SEQ / 64, B_N), 256, 0, stream>>>(X, W, Kswz, Qswz, Vswz);
  attn_kernel<<<dim3(B_N * (T_SEQ / QT)), 512, 0, stream>>>(Kswz, Qswz, Vswz, out);
}

// Round 5
// 105.946 us; speedup vs baseline: 2.0924x; 2.0924x over previous
//
#include <hip/hip_runtime.h>

typedef _Float16 f16;
typedef _Float16 f16x8 __attribute__((ext_vector_type(8)));
typedef __bf16 bf16x8 __attribute__((ext_vector_type(8)));
typedef float floatx4 __attribute__((ext_vector_type(4)));
typedef unsigned short u16;

#define B_N   8
#define T_SEQ 4096
#define DIM   64
#define QT    64     // q rows per block
#define NIT   32     // 4096 / (128 keys per iter: 32 per wave x 4 key-subgroup waves)
#define XSTR  72     // prep LDS row stride in u16
#define LOG2E 1.44269504f
#define FRAG  512    // fragment = 512 u16 (1 KB): lane holds its 8 u16 at lane*8

#if __has_builtin(__builtin_amdgcn_exp2f)
#define EXP2(x) __builtin_amdgcn_exp2f(x)
#else
#define EXP2(x) exp2f(x)
#endif

typedef __attribute__((address_space(1))) const void gvoid;
typedef __attribute__((address_space(3))) void svoid;

// ---- prep: fragment-major Kswz (slot-permuted), Qswz (f16, pre-scaled by log2e),
// ---- Vswz (bf16 V^T B-fragments, identity key order) ----
__launch_bounds__(256, 2)
__global__ void prep_kernel(const float* __restrict__ X, const float* __restrict__ W,
                            u16* __restrict__ Kswz, u16* __restrict__ Qswz,
                            u16* __restrict__ Vswz) {
  __shared__ __attribute__((aligned(16))) u16 Xs[DIM * XSTR];  // f16 X tile [t][d]
  __shared__ __attribute__((aligned(16))) u16 Wt[DIM * XSTR];  // f16 W^T [e][d]
  __shared__ __attribute__((aligned(16))) u16 Qs[DIM * XSTR];  // f16 Q tile [t][e]
  const int tid = threadIdx.x;
  const int lane = tid & 63, w = tid >> 6, qd = lane >> 4, ln = lane & 15;
  const int b = blockIdx.y;
  const int t0 = blockIdx.x * 64;
  const long xbase = ((long)b * T_SEQ + t0) * DIM;

  {
    const int r = tid >> 2, c0 = (tid & 3) * 16;
    float v[16];
#pragma unroll
    for (int i = 0; i < 4; i++)
      *(float4*)&v[i * 4] = *(const float4*)(X + xbase + (long)r * DIM + c0 + i * 4);
    u16 h[16];
#pragma unroll
    for (int j = 0; j < 16; j++) h[j] = __builtin_bit_cast(u16, (f16)v[j]);
    *(uint4*)&Xs[r * XSTR + c0] = *(uint4*)&h[0];
    *(uint4*)&Xs[r * XSTR + c0 + 8] = *(uint4*)&h[8];
    float wv[16];
#pragma unroll
    for (int i = 0; i < 4; i++)
      *(float4*)&wv[i * 4] = *(const float4*)(W + r * DIM + c0 + i * 4);
#pragma unroll
    for (int j = 0; j < 16; j++) Wt[(c0 + j) * XSTR + r] = __builtin_bit_cast(u16, (f16)wv[j]);
  }
  __syncthreads();

  // K fragments, SLOT-PERMUTED: S^T C-layout slot s = ct*16 + qd*4 + r holds
  // physical key k(s) = ((s>>2)&3)*8 + (s>>4)*4 + (s&3) so PV's A-fragment
  // position k = qd*8 + ct*4 + r lines up with V's identity key order.
  {
    const int tile = w >> 1, ct = w & 1;           // 4 waves -> 2 tiles x 2 ct
    const int krow = tile * 32 + (ln >> 2) * 8 + ct * 4 + (ln & 3);
    const long F = ((long)b * 128 + blockIdx.x * 2 + tile) * 2 + ct;
#pragma unroll
    for (int ks = 0; ks < 2; ks++) {
      f16x8 kv = *(const f16x8*)&Xs[krow * XSTR + ks * 32 + qd * 8];
      *(f16x8*)(Kswz + (F * 2 + ks) * FRAG + lane * 8) = kv;
    }
  }

  // Q = X@W via MFMA, scaled by log2e, to Qs (wave-local rows)
  {
    const int wq = w * 16;
    floatx4 acc[4];
#pragma unroll
    for (int ct = 0; ct < 4; ct++) acc[ct] = (floatx4)0.0f;
#pragma unroll
    for (int ks = 0; ks < 2; ks++) {
      f16x8 aX = *(const f16x8*)&Xs[(wq + ln) * XSTR + ks * 32 + qd * 8];
#pragma unroll
      for (int ct = 0; ct < 4; ct++) {
        f16x8 bW = *(const f16x8*)&Wt[(ct * 16 + ln) * XSTR + ks * 32 + qd * 8];
        acc[ct] = __builtin_amdgcn_mfma_f32_16x16x32_f16(aX, bW, acc[ct], 0, 0, 0);
      }
    }
#pragma unroll
    for (int ct = 0; ct < 4; ct++)
#pragma unroll
      for (int r = 0; r < 4; r++)
        Qs[(wq + qd * 4 + r) * XSTR + ct * 16 + ln] =
            __builtin_bit_cast(u16, (f16)(acc[ct][r] * LOG2E));
  }

  // V fragments (identity key order): wave w -> d-block Cb = b*4+w
  {
    const long Cb = (long)b * 4 + w;
    const int J0 = blockIdx.x * 2;
#pragma unroll
    for (int J = 0; J < 2; J++) {
      bf16x8 vv;
#pragma unroll
      for (int j = 0; j < 8; j++) {
        f16 hv = __builtin_bit_cast(f16, Xs[(J * 32 + qd * 8 + j) * XSTR + w * 16 + ln]);
        vv[j] = (__bf16)(float)hv;
      }
      *(bf16x8*)(Vswz + (Cb * (T_SEQ / 32) + J0 + J) * FRAG + lane * 8) = vv;
    }
  }

  // Q fragments from Qs (wave-local rows — no barrier needed)
  {
    const long R = (long)b * (T_SEQ / 16) + blockIdx.x * 4 + w;
#pragma unroll
    for (int ks = 0; ks < 2; ks++) {
      f16x8 qv = *(const f16x8*)&Qs[(w * 16 + ln) * XSTR + ks * 32 + qd * 8];
      *(f16x8*)(Qswz + (R * 2 + ks) * FRAG + lane * 8) = qv;
    }
  }
}

// ---- main: 8 waves = 2 q-groups x 4 key-subgroups. K/V staged to LDS via
// global_load_lds (double-buffered, 1 barrier/iter). P stays in registers.
// Per iter: 128 keys (32/wk-subgroup), shared by both q-groups via LDS.
// NOTE: every access to O/aQ/St/pk MUST be compile-time-indexed (rule #20);
// a runtime index homes the array in scratch -> 1 GB of phantom write traffic
// (measured round 4: WRITE_SIZE 1.04e6 KB, 160 us). ----
__launch_bounds__(512, 4)
__global__ void attn_kernel(const u16* __restrict__ Kswz, const u16* __restrict__ Qswz,
                            const u16* __restrict__ Vswz, float* __restrict__ out) {
  // staging: per buf 32 KB = 16 K-frags (16 KB) + 16 V-frags (16 KB), 1 KB each
  __shared__ __attribute__((aligned(16))) char sbuf[2][32768];
  __shared__ float lpart[8][32];
  float* Opart = (float*)&sbuf[0][0];  // epilogue alias: 8*16*68*4 = 34816 B <= 65536

  const int tid = threadIdx.x;
  const int lane = tid & 63;
  const int w = tid >> 6;           // 0..7
  const int qd = lane >> 4;
  const int ln = lane & 15;
  const int wg = w >> 2;            // q-group
  const int wk = w & 3;             // key subgroup
  const int bid = blockIdx.x;
  const int b = bid & 7;            // batch == XCD for L2 affinity
  const int q0 = (bid >> 3) * QT;
  const long bbase = (long)b * T_SEQ * DIM;

  // Q B-fragments pinned: 32 rows x 64 d for this q-group
  f16x8 aQ[2][2];
#pragma unroll
  for (int rb = 0; rb < 2; rb++)
#pragma unroll
    for (int ks = 0; ks < 2; ks++)
      aQ[rb][ks] = *(const f16x8*)(Qswz +
          (((long)b * (T_SEQ / 16) + (q0 >> 4) + wg * 2 + rb) * 2 + ks) * FRAG + lane * 8);

  // staging source bases (per-lane byte pointers)
  // K tile tau = t*4 + wk' lives at b*524288 + tau*4096 (4 x 1KB frags, i = ct*2+ks)
  // V frag (db, tau) at b*524288 + db*131072 + tau*1024  [wave 4..7 stages, i = db]
  const char* gKw = (const char*)Kswz + (long)b * 524288 + (long)w * 4096 + lane * 16;
  const char* gVw = (const char*)Vswz + (long)b * 524288 + (long)(w - 4) * 1024 + lane * 16;

#define STAGE(bufv, t)                                                                  \
  do {                                                                                  \
    if (w < 4) {                                                                        \
      const char* g = gKw + (long)(t) * 16384;                                          \
      char* l = &sbuf[bufv][w * 4096];                                                  \
      _Pragma("unroll") for (int i = 0; i < 4; i++)                                     \
          __builtin_amdgcn_global_load_lds((gvoid*)(g + i * 1024), (svoid*)(l + i * 1024), \
                                           16, 0, 0);                                   \
    } else {                                                                            \
      const char* g = gVw + (long)(t) * 4096;                                           \
      char* l = &sbuf[bufv][16384 + (w - 4) * 4096];                                    \
      _Pragma("unroll") for (int i = 0; i < 4; i++)                                     \
          __builtin_amdgcn_global_load_lds((gvoid*)(g + i * 131072), (svoid*)(l + i * 1024), \
                                           16, 0, 0);                                   \
    }                                                                                   \
  } while (0)

  floatx4 O[2][4];                  // [q 16-block][d 16-block], 32q x 64d per wave
  float lacc[2] = {0.f, 0.f};
#pragma unroll
  for (int rb = 0; rb < 2; rb++)
#pragma unroll
    for (int db = 0; db < 4; db++) O[rb][db] = (floatx4)0.0f;

  STAGE(0, 0);
  __syncthreads();

  int buf = 0;
#pragma unroll 1
  for (int t = 0; t < NIT; t++) {
    // prefetch next tile into the other buffer (async, drains at syncthreads)
    if (t + 1 < NIT) STAGE(buf ^ 1, t + 1);

    // LDS -> registers (linear 1 KB fragments: conflict-free b128 reads)
    const char* Kb = &sbuf[buf][wk * 4096];
    const char* Vb = &sbuf[buf][16384 + wk * 4096];
    f16x8 bK[2][2];
#pragma unroll
    for (int ct = 0; ct < 2; ct++)
#pragma unroll
      for (int ks = 0; ks < 2; ks++)
        bK[ct][ks] = *(const f16x8*)(Kb + (ct * 2 + ks) * 1024 + lane * 16);
    bf16x8 bV[4];
#pragma unroll
    for (int db = 0; db < 4; db++)
      bV[db] = *(const bf16x8*)(Vb + db * 1024 + lane * 16);

    // QK^T: S^T[32k x 32q]
    floatx4 St[2][2];
#pragma unroll
    for (int ct = 0; ct < 2; ct++)
#pragma unroll
      for (int rb = 0; rb < 2; rb++) St[ct][rb] = (floatx4)0.0f;
    __builtin_amdgcn_s_setprio(1);
#pragma unroll
    for (int ks = 0; ks < 2; ks++)
#pragma unroll
      for (int ct = 0; ct < 2; ct++)
#pragma unroll
        for (int rb = 0; rb < 2; rb++)
          St[ct][rb] = __builtin_amdgcn_mfma_f32_16x16x32_f16(bK[ct][ks], aQ[rb][ks], St[ct][rb], 0, 0, 0);
    __builtin_amdgcn_s_setprio(0);

    // P = 2^S' in registers: slot (ct,qd,r) -> A-frag element j = ct*4 + r
    bf16x8 pk[2];
#pragma unroll
    for (int rb = 0; rb < 2; rb++) {
      float ps = 0.f;
#pragma unroll
      for (int ct = 0; ct < 2; ct++)
#pragma unroll
        for (int r = 0; r < 4; r++) {
          float p = EXP2(St[ct][rb][r]);
          ps += p;
          pk[rb][ct * 4 + r] = (__bf16)p;
        }
      lacc[rb] += ps;
    }

    // PV: O[32q x 64d] += P[32q x 32k] V[32k x 64d]
    __builtin_amdgcn_s_setprio(1);
#pragma unroll
    for (int rb = 0; rb < 2; rb++)
#pragma unroll
      for (int db = 0; db < 4; db++)
        O[rb][db] = __builtin_amdgcn_mfma_f32_16x16x32_bf16(pk[rb], bV[db], O[rb][db], 0, 0, 0);
    __builtin_amdgcn_s_setprio(0);

    __syncthreads();  // drains vmcnt (stages landed) + lgkm; publishes buf^1
    buf ^= 1;
  }

  // l partials: reduce across qd lanes; lpart[w][q-local 0..31]
#pragma unroll
  for (int rb = 0; rb < 2; rb++) {
    float v = lacc[rb];
    v += __shfl_xor(v, 16, 64);
    v += __shfl_xor(v, 32, 64);
    if (qd == 0) lpart[w][rb * 16 + ln] = v;
  }

  // epilogue: FULLY UNROLLED (rule #20: runtime rb would home O in scratch)
#pragma unroll
  for (int rb = 0; rb < 2; rb++) {
    __syncthreads();  // rb=0: lpart published + last LDS reads done; rb=1: prior reads done
#pragma unroll
    for (int db = 0; db < 4; db++)
#pragma unroll
      for (int r = 0; r < 4; r++)
        Opart[(w * 16 + qd * 4 + r) * 68 + db * 16 + ln] = O[rb][db][r];
    __syncthreads();
    const int wg2 = tid >> 8;         // 0..1
    const int q2 = (tid >> 4) & 15;   // 0..15
    const int d0 = (tid & 15) * 4;    // 0..60
    float4 s = *(const float4*)&Opart[((wg2 * 4 + 0) * 16 + q2) * 68 + d0];
    const float4 s1 = *(const float4*)&Opart[((wg2 * 4 + 1) * 16 + q2) * 68 + d0];
    const float4 s2 = *(const float4*)&Opart[((wg2 * 4 + 2) * 16 + q2) * 68 + d0];
    const float4 s3 = *(const float4*)&Opart[((wg2 * 4 + 3) * 16 + q2) * 68 + d0];
    float l = lpart[wg2 * 4 + 0][rb * 16 + q2] + lpart[wg2 * 4 + 1][rb * 16 + q2] +
              lpart[wg2 * 4 + 2][rb * 16 + q2] + lpart[wg2 * 4 + 3][rb * 16 + q2];
    const float inv = 1.0f / l;
    float4 o;
    o.x = (s.x + s1.x + s2.x + s3.x) * inv;
    o.y = (s.y + s1.y + s2.y + s3.y) * inv;
    o.z = (s.z + s1.z + s2.z + s3.z) * inv;
    o.w = (s.w + s1.w + s2.w + s3.w) * inv;
    *(float4*)(out + bbase + (long)(q0 + wg2 * 32 + rb * 16 + q2) * DIM + d0) = o;
  }
#undef STAGE
}

extern "C" void kernel_launch(void* const* d_in, const int* in_sizes, int n_in,
                              void* d_out, int out_size, void* d_ws, size_t ws_size,
                              hipStream_t stream) {
  const float* X = (const float*)d_in[0];
  const float* W = (const float*)d_in[1];
  float* out = (float*)d_out;
  const size_t SZ = (size_t)B_N * T_SEQ * DIM * 2;  // 4 MB per u16 array
  u16* Kswz = (u16*)d_ws;
  u16* Qswz = (u16*)((char*)d_ws + SZ);
  u16* Vswz = (u16*)((char*)d_ws + 2 * SZ);
  prep_kernel<<<dim3(T_SEQ / 64, B_N), 256, 0, stream>>>(X, W, Kswz, Qswz, Vswz);
  attn_kernel<<<dim3(B_N * (T_SEQ / QT)), 512, 0, stream>>>(Kswz, Qswz, Vswz, out);
}